// Round 5
// baseline (1365.733 us; speedup 1.0000x reference)
//
#include <hip/hip_runtime.h>
#include <stdint.h>

#define HW    480
#define KS    24
#define CH    3
#define HO    457            // 480-24+1
#define NPOS  (HO*HO)        // 208849
#define NP    400
#define PS    (CH*KS*KS)     // 1728
#define SIG   1e-6f
#define NKI   (CH*KS)        // 72 k-iterations (one per (c,kh) row)
#define NMT   13             // 32-patch MFMA tiles (416 padded patches)

typedef __attribute__((ext_vector_type(8))) short short8;
typedef __attribute__((ext_vector_type(16))) float float16v;
typedef unsigned int uint;
typedef unsigned short ushort;
typedef unsigned long long ull;

static __device__ __forceinline__ ushort f2bf(float v) {
    uint u = __float_as_uint(v);
    uint r = (u + 0x7fffu + ((u >> 16) & 1u)) >> 16;   // RNE
    return (ushort)r;
}
static __device__ __forceinline__ float bf2f(ushort h) {
    return __uint_as_float(((uint)h) << 16);
}

// ---------------- prep kernels ----------------

// Repack x_dec patches into Wp[p][c][kh][kw] contiguous (400 x 1728), fp32
__global__ void repack_k(const float* __restrict__ x, float* __restrict__ Wp) {
    int t = blockIdx.x * 256 + threadIdx.x;
    if (t >= NP * PS) return;
    int p = t / PS, e = t - p * PS;
    int c = e / (KS * KS);
    int r = (e / KS) % KS;
    int w = e % KS;
    int pr = p / 20, pc = p - pr * 20;
    Wp[t] = x[c * HW * HW + (pr * KS + r) * HW + (pc * KS + w)];
}

// Per-patch mean and |den_x|
__global__ void stats_k(const float* __restrict__ Wp,
                        float* __restrict__ meanX, float* __restrict__ denXa) {
    __shared__ float shs[4], shs2[4];
    int p = blockIdx.x;
    float s = 0.f, s2 = 0.f;
    for (int e = threadIdx.x; e < PS; e += 256) {
        float v = Wp[p * PS + e];
        s += v; s2 += v * v;
    }
    for (int o = 32; o > 0; o >>= 1) { s += __shfl_down(s, o); s2 += __shfl_down(s2, o); }
    int lane = threadIdx.x & 63, wv = threadIdx.x >> 6;
    if (lane == 0) { shs[wv] = s; shs2[wv] = s2; }
    __syncthreads();
    if (threadIdx.x == 0) {
        float S = shs[0] + shs[1] + shs[2] + shs[3];
        float S2 = shs2[0] + shs2[1] + shs2[2] + shs2[3];
        float m = S / (float)PS;
        meanX[p] = m;
        denXa[p] = fabsf(S2 / (float)PS - m * m);
    }
}

// y_dec -> interleaved bf16 planes: yhl[pix] = hi | (lo<<16)
__global__ void split_y_k(const float* __restrict__ y, uint* __restrict__ yhl) {
    int t = blockIdx.x * 256 + threadIdx.x;
    if (t >= CH * HW * HW) return;
    float v = y[t];
    ushort h = f2bf(v);
    ushort l = f2bf(v - bf2f(h));
    yhl[t] = (uint)h | ((uint)l << 16);
}

// Pack A fragments for 32x32x16: frag f = (mtg*72 + ki)*8 + (t*4 + pl*2 + ks)
// 512 bf16 per frag, element at lane*8 + e.
// A[m][k]: m = lane&31, k = (lane>>5)*8 + e  (k in [0,16) of kstep ks)
// padded kw' = ks*16 + k; real kw = kw' - t; zero outside [0,24) or p>=400.
__global__ void packA_k(const float* __restrict__ Wp, ushort* __restrict__ Ap) {
    int id = blockIdx.x * 256 + threadIdx.x;
    if (id >= NMT * NKI * 8 * 512) return;
    int e  = id & 7;
    int L  = (id >> 3) & 63;
    int f  = id >> 9;
    int ks = f & 1;
    int pl = (f >> 1) & 1;
    int t  = (f >> 2) & 1;
    int rest = f >> 3;
    int ki  = rest % NKI;
    int mtg = rest / NKI;
    int m = L & 31, kha = L >> 5;
    int kwp = ks * 16 + kha * 8 + e;
    int kw = kwp - t;
    int p = mtg * 32 + m;
    float v = 0.f;
    if (p < NP && kw >= 0 && kw < KS)
        v = Wp[p * PS + ki * KS + kw];
    ushort h = f2bf(v);
    Ap[id] = pl ? f2bf(v - bf2f(h)) : h;
}

// Vertical 24-row sums of y_dec (channels folded): cs/cs2 are (457 x 480)
__global__ void colsum_k(const float* __restrict__ y,
                         float* __restrict__ cs, float* __restrict__ cs2) {
    int t = blockIdx.x * 256 + threadIdx.x;
    if (t >= HO * HW) return;
    int i = t / HW, w = t - i * HW;
    float s = 0.f, s2 = 0.f;
    for (int c = 0; c < CH; c++) {
        const float* base = y + c * HW * HW + i * HW + w;
        for (int dh = 0; dh < KS; dh++) {
            float v = base[dh * HW];
            s += v; s2 += v * v;
        }
    }
    cs[t] = s; cs2[t] = s2;
}

// Horizontal 24-col sums -> sumY, |den_y| per position (457 x 457)
__global__ void window_k(const float* __restrict__ cs, const float* __restrict__ cs2,
                         float* __restrict__ sumY, float* __restrict__ denYa) {
    int t = blockIdx.x * 256 + threadIdx.x;
    if (t >= NPOS) return;
    int i = t / HO, j = t - i * HO;
    const float* r  = cs  + i * HW + j;
    const float* r2 = cs2 + i * HW + j;
    float s = 0.f, s2 = 0.f;
    for (int d = 0; d < KS; d++) { s += r[d]; s2 += r2[d]; }
    sumY[t] = s;
    float ips = 1.0f / (float)PS;
    denYa[t] = fabsf(s2 * ips - (s * ips) * (s * ips));
}

// ---------------- main 32x32x16 MFMA correlation + argmax ----------------
// grid(2=jt, 229=row-pair, 13=mtg). Block: 256 thr = 4 waves, ALL same mtg
// (A frags L1-shared). Wave g covers 64 positions j = j0 + 64g + 2n + t
// (t=0..1 absorbed into pre-shifted A copies) x 2 i-rows.
// acc[t][ri] = 4 x 16 fp32 = 64 AGPR -> 3 waves/SIMD for latency hiding.
__launch_bounds__(256, 3)
__global__ void corr32_k(const uint* __restrict__ yhl, const ushort* __restrict__ Ap,
                         const float* __restrict__ meanX, const float* __restrict__ denXa,
                         const float* __restrict__ sumY, const float* __restrict__ denYa,
                         ull* __restrict__ best) {
    __shared__ ushort Bh[25 * 288];
    __shared__ ushort Bl[25 * 288];

    const int tid  = threadIdx.x;
    const int lane = tid & 63;
    const int g    = tid >> 6;      // wave = j-subtile
    const int n    = lane & 31;     // MFMA column (position sub-index)
    const int kha  = lane >> 5;     // k-half / C-row-half selector
    const int j0   = blockIdx.x ? 204 : 0;   // 4-aligned; jt1 cols 204..459 (j>=457 masked)
    const int i0   = blockIdx.y * 2;
    const int mtg  = blockIdx.z;
    const int jb   = j0 + 64 * g;
    const bool ri1ok = (i0 + 1) < HO;

    float16v acc[2][2];   // [t][ri]
#pragma unroll
    for (int t = 0; t < 2; t++)
#pragma unroll
        for (int ri = 0; ri < 2; ri++) acc[t][ri] = (float16v)0.f;

    for (int c = 0; c < CH; c++) {
        __syncthreads();   // previous chunk fully consumed
        // stage 25 rows x 288 cols (uint4 granules, 72 per row)
        for (int it = tid; it < 25 * 72; it += 256) {
            int d  = it / 72;
            int c4 = (it - d * 72) * 4;
            int yr = i0 + d;
            int gj = j0 + c4;
            uint4 u = make_uint4(0, 0, 0, 0);
            if (yr < HW) {
                const uint* q = yhl + c * HW * HW + yr * HW;
                if (gj + 3 < HW) u = *(const uint4*)(q + gj);   // 16B-aligned (j0%4==0)
                else {
                    if (gj + 0 < HW) u.x = q[gj + 0];
                    if (gj + 1 < HW) u.y = q[gj + 1];
                    if (gj + 2 < HW) u.z = q[gj + 2];
                }
            }
            ushort4 h4, l4;
            h4.x = (ushort)(u.x & 0xffff); l4.x = (ushort)(u.x >> 16);
            h4.y = (ushort)(u.y & 0xffff); l4.y = (ushort)(u.y >> 16);
            h4.z = (ushort)(u.z & 0xffff); l4.z = (ushort)(u.z >> 16);
            h4.w = (ushort)(u.w & 0xffff); l4.w = (ushort)(u.w >> 16);
            *(ushort4*)&Bh[d * 288 + c4] = h4;
            *(ushort4*)&Bl[d * 288 + c4] = l4;
        }
        __syncthreads();

        for (int kh = 0; kh < KS; kh++) {
            const int ki = c * KS + kh;
            const ushort* fb = Ap + (((size_t)(mtg * NKI + ki)) << 12) + lane * 8;
            short8 af[2][2][2];   // [t][pl][ks]
#pragma unroll
            for (int t = 0; t < 2; t++)
#pragma unroll
                for (int pl = 0; pl < 2; pl++)
#pragma unroll
                    for (int ks = 0; ks < 2; ks++)
                        af[t][pl][ks] = *(const short8*)(fb + (((t << 2) | (pl << 1) | ks) << 9));

#pragma unroll
            for (int ks = 0; ks < 2; ks++) {
                const int colb = 64 * g + 16 * ks + 8 * kha + 2 * n;
#pragma unroll
                for (int ri = 0; ri < 2; ri++) {
                    const int d = kh + ri;
                    const uint* ph = (const uint*)&Bh[d * 288 + colb];
                    const uint* pq = (const uint*)&Bl[d * 288 + colb];
                    union { uint u[4]; short8 v; } bh, bl;
#pragma unroll
                    for (int q = 0; q < 4; q++) { bh.u[q] = ph[q]; bl.u[q] = pq[q]; }
#pragma unroll
                    for (int t = 0; t < 2; t++) {
                        acc[t][ri] = __builtin_amdgcn_mfma_f32_32x32x16_bf16(af[t][0][ks], bh.v, acc[t][ri], 0, 0, 0);
                        acc[t][ri] = __builtin_amdgcn_mfma_f32_32x32x16_bf16(af[t][0][ks], bl.v, acc[t][ri], 0, 0, 0);
                        acc[t][ri] = __builtin_amdgcn_mfma_f32_32x32x16_bf16(af[t][1][ks], bh.v, acc[t][ri], 0, 0, 0);
                    }
                }
            }
        }
    }

    // ---- epilogue: corr + packed argmax ----
    const float invps = 1.0f / (float)PS;
    const int pbase = mtg * 32;
    float mXv[16], dXv[16];
#pragma unroll
    for (int r = 0; r < 16; r++) {
        int p = pbase + (r & 3) + 8 * (r >> 2) + 4 * kha;
        bool ok = p < NP;
        mXv[r] = ok ? meanX[p] : 0.f;
        dXv[r] = ok ? denXa[p] : 0.f;
    }
    float sYv[2][2], dYv[2][2];
#pragma unroll
    for (int ri = 0; ri < 2; ri++) {
        bool iok = (ri == 0) || ri1ok;
        int ib = (i0 + ri) * HO;
#pragma unroll
        for (int t = 0; t < 2; t++) {
            int j = jb + 2 * n + t;
            bool ok = iok && (j < HO);
            sYv[ri][t] = ok ? sumY[ib + j] : 0.f;
            dYv[ri][t] = ok ? denYa[ib + j] : 0.f;
        }
    }
#pragma unroll
    for (int r = 0; r < 16; r++) {
        ull bp = 0ull;
#pragma unroll
        for (int ri = 0; ri < 2; ri++) {
            if (ri == 1 && !ri1ok) continue;
#pragma unroll
            for (int t = 0; t < 2; t++) {
                int j = jb + 2 * n + t;
                if (j < HO) {
                    float xy = acc[t][ri][r];
                    float corr = (2.0f * (xy - mXv[r] * sYv[ri][t]) * invps + SIG)
                               / (dXv[r] + dYv[ri][t] + SIG);
                    uint ub = __float_as_uint(corr);
                    ub = (ub & 0x80000000u) ? ~ub : (ub | 0x80000000u);
                    uint idx = (uint)((i0 + ri) * HO + j);
                    ull pk = ((ull)ub << 32) | (uint)(~idx);
                    bp = pk > bp ? pk : bp;
                }
            }
        }
        // reduce across the 32 lanes (cols) of this kha-half
#pragma unroll
        for (int o = 1; o < 32; o <<= 1) {
            ull other = __shfl_xor(bp, o);
            bp = other > bp ? other : bp;
        }
        if (n == 0) {
            int p = pbase + (r & 3) + 8 * (r >> 2) + 4 * kha;
            if (p < NP) atomicMax(&best[p], bp);
        }
    }
}

// ---------------- gather ----------------
__global__ void gather_k(const float* __restrict__ y,
                         const ull* __restrict__ best,
                         float* __restrict__ out) {
    int p = blockIdx.x;
    uint idx = ~((uint)(best[p] & 0xFFFFFFFFull));
    int r = idx / HO, cc = idx - r * HO;
    int pr = p / 20, pc = p - pr * 20;
    for (int e = threadIdx.x; e < PS; e += 256) {
        int c = e / (KS * KS);
        int kh = (e / KS) % KS;
        int kw = e % KS;
        out[c * HW * HW + (pr * KS + kh) * HW + (pc * KS + kw)] =
            y[c * HW * HW + (r + kh) * HW + (cc + kw)];
    }
}

// ---------------- launch ----------------
extern "C" void kernel_launch(void* const* d_in, const int* in_sizes, int n_in,
                              void* d_out, int out_size, void* d_ws, size_t ws_size,
                              hipStream_t stream) {
    const float* x_dec = (const float*)d_in[0];
    const float* y_dec = (const float*)d_in[1];
    const float* y     = (const float*)d_in[2];
    float* out = (float*)d_out;

    char* ws = (char*)d_ws;
    size_t off = 0;
    auto carve = [&](size_t bytes) -> void* {
        void* p = ws + off;
        off += (bytes + 255) & ~(size_t)255;
        return p;
    };
    float* Wp    = (float*)carve((size_t)NP * PS * 4);            // 2.76 MB
    uint*  yhl   = (uint*)carve((size_t)CH * HW * HW * 4);        // 2.76 MB
    ushort* Ap   = (ushort*)carve((size_t)NMT * NKI * 8 * 512 * 2); // 7.67 MB
    float* cs    = (float*)carve((size_t)HO * HW * 4);
    float* cs2   = (float*)carve((size_t)HO * HW * 4);
    float* sumY  = (float*)carve((size_t)NPOS * 4);
    float* denYa = (float*)carve((size_t)NPOS * 4);
    float* meanX = (float*)carve((size_t)NP * 4);
    float* denXa = (float*)carve((size_t)NP * 4);
    ull*   best  = (ull*)carve((size_t)NP * 8);

    hipMemsetAsync(best, 0, (size_t)NP * 8, stream);

    repack_k<<<(NP * PS + 255) / 256, 256, 0, stream>>>(x_dec, Wp);
    stats_k<<<NP, 256, 0, stream>>>(Wp, meanX, denXa);
    split_y_k<<<(CH * HW * HW + 255) / 256, 256, 0, stream>>>(y_dec, yhl);
    packA_k<<<(NMT * NKI * 8 * 512 + 255) / 256, 256, 0, stream>>>(Wp, Ap);
    colsum_k<<<(HO * HW + 255) / 256, 256, 0, stream>>>(y_dec, cs, cs2);
    window_k<<<(NPOS + 255) / 256, 256, 0, stream>>>(cs, cs2, sumY, denYa);

    dim3 grid(2, 229, NMT);
    corr32_k<<<grid, 256, 0, stream>>>(yhl, Ap, meanX, denXa, sumY, denYa, best);

    gather_k<<<NP, 256, 0, stream>>>(y, best, out);
}

// Round 6
// 1311.107 us; speedup vs baseline: 1.0417x; 1.0417x over previous
//
#include <hip/hip_runtime.h>
#include <stdint.h>

#define HW    480
#define KS    24
#define CH    3
#define HO    457            // 480-24+1
#define NPOS  (HO*HO)        // 208849
#define NP    400
#define PS    (CH*KS*KS)     // 1728
#define SIG   1e-6f
#define NKI   (CH*KS)        // 72 k-iterations (one per (c,kh) row)
#define NMT   14             // 32-patch MFMA tiles (448 padded patches)

typedef __attribute__((ext_vector_type(8))) short short8;
typedef __attribute__((ext_vector_type(16))) float float16v;
typedef unsigned int uint;
typedef unsigned short ushort;
typedef unsigned long long ull;

static __device__ __forceinline__ ushort f2bf(float v) {
    uint u = __float_as_uint(v);
    uint r = (u + 0x7fffu + ((u >> 16) & 1u)) >> 16;   // RNE
    return (ushort)r;
}
static __device__ __forceinline__ float bf2f(ushort h) {
    return __uint_as_float(((uint)h) << 16);
}

// ---------------- prep kernels ----------------

__global__ void repack_k(const float* __restrict__ x, float* __restrict__ Wp) {
    int t = blockIdx.x * 256 + threadIdx.x;
    if (t >= NP * PS) return;
    int p = t / PS, e = t - p * PS;
    int c = e / (KS * KS);
    int r = (e / KS) % KS;
    int w = e % KS;
    int pr = p / 20, pc = p - pr * 20;
    Wp[t] = x[c * HW * HW + (pr * KS + r) * HW + (pc * KS + w)];
}

__global__ void stats_k(const float* __restrict__ Wp,
                        float* __restrict__ meanX, float* __restrict__ denXa) {
    __shared__ float shs[4], shs2[4];
    int p = blockIdx.x;
    float s = 0.f, s2 = 0.f;
    for (int e = threadIdx.x; e < PS; e += 256) {
        float v = Wp[p * PS + e];
        s += v; s2 += v * v;
    }
    for (int o = 32; o > 0; o >>= 1) { s += __shfl_down(s, o); s2 += __shfl_down(s2, o); }
    int lane = threadIdx.x & 63, wv = threadIdx.x >> 6;
    if (lane == 0) { shs[wv] = s; shs2[wv] = s2; }
    __syncthreads();
    if (threadIdx.x == 0) {
        float S = shs[0] + shs[1] + shs[2] + shs[3];
        float S2 = shs2[0] + shs2[1] + shs2[2] + shs2[3];
        float m = S / (float)PS;
        meanX[p] = m;
        denXa[p] = fabsf(S2 / (float)PS - m * m);
    }
}

// y_dec -> interleaved bf16 planes: yhl[pix] = hi | (lo<<16)
__global__ void split_y_k(const float* __restrict__ y, uint* __restrict__ yhl) {
    int t = blockIdx.x * 256 + threadIdx.x;
    if (t >= CH * HW * HW) return;
    float v = y[t];
    ushort h = f2bf(v);
    ushort l = f2bf(v - bf2f(h));
    yhl[t] = (uint)h | ((uint)l << 16);
}

// Pack A fragments for 32x32x16: frag f = (mtg*72 + ki)*8 + (t*4 + pl*2 + ks)
// 512 bf16 per frag, element at lane*8 + e.  A[m][k]: m = lane&31,
// k = (lane>>5)*8 + e; padded kw' = ks*16 + k; real kw = kw' - t.
__global__ void packA_k(const float* __restrict__ Wp, ushort* __restrict__ Ap) {
    int id = blockIdx.x * 256 + threadIdx.x;
    if (id >= NMT * NKI * 8 * 512) return;
    int e  = id & 7;
    int L  = (id >> 3) & 63;
    int f  = id >> 9;
    int ks = f & 1;
    int pl = (f >> 1) & 1;
    int t  = (f >> 2) & 1;
    int rest = f >> 3;
    int ki  = rest % NKI;
    int mtg = rest / NKI;
    int m = L & 31, kha = L >> 5;
    int kwp = ks * 16 + kha * 8 + e;
    int kw = kwp - t;
    int p = mtg * 32 + m;
    float v = 0.f;
    if (p < NP && kw >= 0 && kw < KS)
        v = Wp[p * PS + ki * KS + kw];
    ushort h = f2bf(v);
    Ap[id] = pl ? f2bf(v - bf2f(h)) : h;
}

__global__ void colsum_k(const float* __restrict__ y,
                         float* __restrict__ cs, float* __restrict__ cs2) {
    int t = blockIdx.x * 256 + threadIdx.x;
    if (t >= HO * HW) return;
    int i = t / HW, w = t - i * HW;
    float s = 0.f, s2 = 0.f;
    for (int c = 0; c < CH; c++) {
        const float* base = y + c * HW * HW + i * HW + w;
        for (int dh = 0; dh < KS; dh++) {
            float v = base[dh * HW];
            s += v; s2 += v * v;
        }
    }
    cs[t] = s; cs2[t] = s2;
}

__global__ void window_k(const float* __restrict__ cs, const float* __restrict__ cs2,
                         float* __restrict__ sumY, float* __restrict__ denYa) {
    int t = blockIdx.x * 256 + threadIdx.x;
    if (t >= NPOS) return;
    int i = t / HO, j = t - i * HO;
    const float* r  = cs  + i * HW + j;
    const float* r2 = cs2 + i * HW + j;
    float s = 0.f, s2 = 0.f;
    for (int d = 0; d < KS; d++) { s += r[d]; s2 += r2[d]; }
    sumY[t] = s;
    float ips = 1.0f / (float)PS;
    denYa[t] = fabsf(s2 * ips - (s * ips) * (s * ips));
}

// ---------------- main 32x32x16 MFMA correlation + argmax ----------------
// grid(4=jt, 153=row-triple, 7=mtg-pair). Block: 256 thr = 4 waves =
// 2 j-chunks (cw) x 2 mtg (mw). Wave: 32 patches x 64 positions
// (j = j0 + 64cw + 2n + t) x 3 i-rows (ri).
// B in LDS with a 4-byte-shifted duplicate copy so every lane's 16B frag is
// 8B-aligned -> 2x ds_read_b64 (2-way bank aliasing = free).
// acc[t2][ri3] = 96 AGPR -> 3 waves/SIMD.
__launch_bounds__(256, 3)
__global__ void corr32_k(const uint* __restrict__ yhl, const ushort* __restrict__ Ap,
                         const float* __restrict__ meanX, const float* __restrict__ denXa,
                         const float* __restrict__ sumY, const float* __restrict__ denYa,
                         ull* __restrict__ best) {
    __shared__ ushort Bh0[26 * 160];
    __shared__ ushort Bh1[26 * 160];   // Bh1[i] = row[i+2] (4-byte shift)
    __shared__ ushort Bl0[26 * 160];
    __shared__ ushort Bl1[26 * 160];

    const int tid  = threadIdx.x;
    const int lane = tid & 63;
    const int g    = tid >> 6;
    const int n    = lane & 31;     // MFMA column
    const int kha  = lane >> 5;     // k-half selector
    const int cw   = g & 1;         // j-chunk of block
    const int mw   = g >> 1;        // mtg within pair
    static const int j0tab[4] = {0, 128, 256, 332};
    const int j0   = j0tab[blockIdx.x];
    const int i0   = blockIdx.y * 3;
    const int mtg  = blockIdx.z * 2 + mw;

    // odd lanes use the shifted copy (pre-offset -2 so index math is shared)
    const ushort* baseH = (n & 1) ? (Bh1 - 2) : Bh0;
    const ushort* baseL = (n & 1) ? (Bl1 - 2) : Bl0;
    const int coloff = 64 * cw + 8 * kha + 2 * n;

    float16v acc[2][3];   // [t][ri]
#pragma unroll
    for (int t = 0; t < 2; t++)
#pragma unroll
        for (int ri = 0; ri < 3; ri++) acc[t][ri] = (float16v)0.f;

    for (int c = 0; c < CH; c++) {
        __syncthreads();   // previous chunk fully consumed
        // stage 26 rows x 160 cols (hi/lo + shifted copies)
        for (int it = tid; it < 26 * 40; it += 256) {
            int d  = it / 40;
            int c4 = (it - d * 40) * 4;
            int yr = i0 + d;
            int gj = j0 + c4;
            uint4 u = make_uint4(0, 0, 0, 0);
            if (yr < HW) {
                const uint* q = yhl + c * HW * HW + yr * HW;
                if (gj + 3 < HW) u = *(const uint4*)(q + gj);   // j0 % 4 == 0
                else {
                    if (gj + 0 < HW) u.x = q[gj + 0];
                    if (gj + 1 < HW) u.y = q[gj + 1];
                    if (gj + 2 < HW) u.z = q[gj + 2];
                }
            }
            ushort4 h4, l4;
            h4.x = (ushort)(u.x & 0xffff); l4.x = (ushort)(u.x >> 16);
            h4.y = (ushort)(u.y & 0xffff); l4.y = (ushort)(u.y >> 16);
            h4.z = (ushort)(u.z & 0xffff); l4.z = (ushort)(u.z >> 16);
            h4.w = (ushort)(u.w & 0xffff); l4.w = (ushort)(u.w >> 16);
            *(ushort4*)&Bh0[d * 160 + c4] = h4;
            *(ushort4*)&Bl0[d * 160 + c4] = l4;
            // shifted copy: Bx1[i] = row[i+2]
            uint hlo = (uint)h4.x | ((uint)h4.y << 16);
            uint hhi = (uint)h4.z | ((uint)h4.w << 16);
            uint llo = (uint)l4.x | ((uint)l4.y << 16);
            uint lhi = (uint)l4.z | ((uint)l4.w << 16);
            if (c4 > 0) {
                *(uint*)&Bh1[d * 160 + c4 - 2] = hlo;
                *(uint*)&Bl1[d * 160 + c4 - 2] = llo;
            }
            *(uint*)&Bh1[d * 160 + c4] = hhi;
            *(uint*)&Bl1[d * 160 + c4] = lhi;
        }
        __syncthreads();

        for (int kh = 0; kh < KS; kh++) {
            const int ki = c * KS + kh;
            const ushort* fb = Ap + (((size_t)(mtg * NKI + ki)) << 12) + lane * 8;
            short8 af[2][2][2];   // [t][pl][ks]
#pragma unroll
            for (int t = 0; t < 2; t++)
#pragma unroll
                for (int pl = 0; pl < 2; pl++)
#pragma unroll
                    for (int ks = 0; ks < 2; ks++)
                        af[t][pl][ks] = *(const short8*)(fb + (((t << 2) | (pl << 1) | ks) << 9));

#pragma unroll
            for (int ks = 0; ks < 2; ks++) {
#pragma unroll
                for (int ri = 0; ri < 3; ri++) {
                    const int d = kh + ri;
                    const int idx = d * 160 + coloff + 16 * ks;
                    union { uint2 q[2]; short8 v; } bh, bl;
                    bh.q[0] = *(const uint2*)(baseH + idx);
                    bh.q[1] = *(const uint2*)(baseH + idx + 4);
                    bl.q[0] = *(const uint2*)(baseL + idx);
                    bl.q[1] = *(const uint2*)(baseL + idx + 4);
#pragma unroll
                    for (int t = 0; t < 2; t++) {
                        acc[t][ri] = __builtin_amdgcn_mfma_f32_32x32x16_bf16(af[t][0][ks], bh.v, acc[t][ri], 0, 0, 0);
                        acc[t][ri] = __builtin_amdgcn_mfma_f32_32x32x16_bf16(af[t][0][ks], bl.v, acc[t][ri], 0, 0, 0);
                        acc[t][ri] = __builtin_amdgcn_mfma_f32_32x32x16_bf16(af[t][1][ks], bh.v, acc[t][ri], 0, 0, 0);
                    }
                }
            }
        }
    }

    // ---- epilogue: corr + packed argmax ----
    const float invps = 1.0f / (float)PS;
    const int pbase = mtg * 32;
    const int jb = j0 + 64 * cw;
    float mXv[16], dXv[16];
#pragma unroll
    for (int r = 0; r < 16; r++) {
        int p = pbase + (r & 3) + 8 * (r >> 2) + 4 * kha;
        bool ok = p < NP;
        mXv[r] = ok ? meanX[p] : 0.f;
        dXv[r] = ok ? denXa[p] : 0.f;
    }
    float sYv[3][2], dYv[3][2];
#pragma unroll
    for (int ri = 0; ri < 3; ri++) {
        bool iok = (i0 + ri) < HO;
        int ib = (i0 + ri) * HO;
#pragma unroll
        for (int t = 0; t < 2; t++) {
            int j = jb + 2 * n + t;
            bool ok = iok && (j < HO);
            sYv[ri][t] = ok ? sumY[ib + j] : 0.f;
            dYv[ri][t] = ok ? denYa[ib + j] : 0.f;
        }
    }
#pragma unroll
    for (int r = 0; r < 16; r++) {
        ull bp = 0ull;
#pragma unroll
        for (int ri = 0; ri < 3; ri++) {
            if ((i0 + ri) >= HO) continue;
#pragma unroll
            for (int t = 0; t < 2; t++) {
                int j = jb + 2 * n + t;
                if (j < HO) {
                    float xy = acc[t][ri][r];
                    float corr = (2.0f * (xy - mXv[r] * sYv[ri][t]) * invps + SIG)
                               / (dXv[r] + dYv[ri][t] + SIG);
                    uint ub = __float_as_uint(corr);
                    ub = (ub & 0x80000000u) ? ~ub : (ub | 0x80000000u);
                    uint idx = (uint)((i0 + ri) * HO + j);
                    ull pk = ((ull)ub << 32) | (uint)(~idx);
                    bp = pk > bp ? pk : bp;
                }
            }
        }
#pragma unroll
        for (int o = 1; o < 32; o <<= 1) {
            ull other = __shfl_xor(bp, o);
            bp = other > bp ? other : bp;
        }
        if (n == 0) {
            int p = pbase + (r & 3) + 8 * (r >> 2) + 4 * kha;
            if (p < NP) atomicMax(&best[p], bp);
        }
    }
}

// ---------------- gather ----------------
__global__ void gather_k(const float* __restrict__ y,
                         const ull* __restrict__ best,
                         float* __restrict__ out) {
    int p = blockIdx.x;
    uint idx = ~((uint)(best[p] & 0xFFFFFFFFull));
    int r = idx / HO, cc = idx - r * HO;
    int pr = p / 20, pc = p - pr * 20;
    for (int e = threadIdx.x; e < PS; e += 256) {
        int c = e / (KS * KS);
        int kh = (e / KS) % KS;
        int kw = e % KS;
        out[c * HW * HW + (pr * KS + kh) * HW + (pc * KS + kw)] =
            y[c * HW * HW + (r + kh) * HW + (cc + kw)];
    }
}

// ---------------- launch ----------------
extern "C" void kernel_launch(void* const* d_in, const int* in_sizes, int n_in,
                              void* d_out, int out_size, void* d_ws, size_t ws_size,
                              hipStream_t stream) {
    const float* x_dec = (const float*)d_in[0];
    const float* y_dec = (const float*)d_in[1];
    const float* y     = (const float*)d_in[2];
    float* out = (float*)d_out;

    char* ws = (char*)d_ws;
    size_t off = 0;
    auto carve = [&](size_t bytes) -> void* {
        void* p = ws + off;
        off += (bytes + 255) & ~(size_t)255;
        return p;
    };
    float* Wp    = (float*)carve((size_t)NP * PS * 4);            // 2.76 MB
    uint*  yhl   = (uint*)carve((size_t)CH * HW * HW * 4);        // 2.76 MB
    ushort* Ap   = (ushort*)carve((size_t)NMT * NKI * 8 * 512 * 2); // 8.26 MB
    float* cs    = (float*)carve((size_t)HO * HW * 4);
    float* cs2   = (float*)carve((size_t)HO * HW * 4);
    float* sumY  = (float*)carve((size_t)NPOS * 4);
    float* denYa = (float*)carve((size_t)NPOS * 4);
    float* meanX = (float*)carve((size_t)NP * 4);
    float* denXa = (float*)carve((size_t)NP * 4);
    ull*   best  = (ull*)carve((size_t)NP * 8);

    hipMemsetAsync(best, 0, (size_t)NP * 8, stream);

    repack_k<<<(NP * PS + 255) / 256, 256, 0, stream>>>(x_dec, Wp);
    stats_k<<<NP, 256, 0, stream>>>(Wp, meanX, denXa);
    split_y_k<<<(CH * HW * HW + 255) / 256, 256, 0, stream>>>(y_dec, yhl);
    packA_k<<<(NMT * NKI * 8 * 512 + 255) / 256, 256, 0, stream>>>(Wp, Ap);
    colsum_k<<<(HO * HW + 255) / 256, 256, 0, stream>>>(y_dec, cs, cs2);
    window_k<<<(NPOS + 255) / 256, 256, 0, stream>>>(cs, cs2, sumY, denYa);

    dim3 grid(4, 153, 7);
    corr32_k<<<grid, 256, 0, stream>>>(yhl, Ap, meanX, denXa, sumY, denYa, best);

    gather_k<<<NP, 256, 0, stream>>>(y, best, out);
}

// Round 7
// 959.561 us; speedup vs baseline: 1.4233x; 1.3664x over previous
//
#include <hip/hip_runtime.h>
#include <stdint.h>

#define HW    480
#define KS    24
#define CH    3
#define HO    457            // 480-24+1
#define NPOS  (HO*HO)        // 208849
#define NP    400
#define PS    (CH*KS*KS)     // 1728
#define SIG   1e-6f
#define NST   108            // exact K16 steps: 1728/16
#define NMT   14             // 32-patch MFMA tiles (448 padded patches)

typedef __attribute__((ext_vector_type(8))) short short8;
typedef __attribute__((ext_vector_type(16))) float float16v;
typedef unsigned int uint;
typedef unsigned short ushort;
typedef unsigned long long ull;

static __device__ __forceinline__ ushort f2bf(float v) {
    uint u = __float_as_uint(v);
    uint r = (u + 0x7fffu + ((u >> 16) & 1u)) >> 16;   // RNE
    return (ushort)r;
}
static __device__ __forceinline__ float bf2f(ushort h) {
    return __uint_as_float(((uint)h) << 16);
}

// ---------------- prep kernels ----------------

__global__ void repack_k(const float* __restrict__ x, float* __restrict__ Wp) {
    int t = blockIdx.x * 256 + threadIdx.x;
    if (t >= NP * PS) return;
    int p = t / PS, e = t - p * PS;
    int c = e / (KS * KS);
    int r = (e / KS) % KS;
    int w = e % KS;
    int pr = p / 20, pc = p - pr * 20;
    Wp[t] = x[c * HW * HW + (pr * KS + r) * HW + (pc * KS + w)];
}

__global__ void stats_k(const float* __restrict__ Wp,
                        float* __restrict__ meanX, float* __restrict__ denXa) {
    __shared__ float shs[4], shs2[4];
    int p = blockIdx.x;
    float s = 0.f, s2 = 0.f;
    for (int e = threadIdx.x; e < PS; e += 256) {
        float v = Wp[p * PS + e];
        s += v; s2 += v * v;
    }
    for (int o = 32; o > 0; o >>= 1) { s += __shfl_down(s, o); s2 += __shfl_down(s2, o); }
    int lane = threadIdx.x & 63, wv = threadIdx.x >> 6;
    if (lane == 0) { shs[wv] = s; shs2[wv] = s2; }
    __syncthreads();
    if (threadIdx.x == 0) {
        float S = shs[0] + shs[1] + shs[2] + shs[3];
        float S2 = shs2[0] + shs2[1] + shs2[2] + shs2[3];
        float m = S / (float)PS;
        meanX[p] = m;
        denXa[p] = fabsf(S2 / (float)PS - m * m);
    }
}

// y_dec -> interleaved bf16 planes: yhl[pix] = hi | (lo<<16)
__global__ void split_y_k(const float* __restrict__ y, uint* __restrict__ yhl) {
    int t = blockIdx.x * 256 + threadIdx.x;
    if (t >= CH * HW * HW) return;
    float v = y[t];
    ushort h = f2bf(v);
    ushort l = f2bf(v - bf2f(h));
    yhl[t] = (uint)h | ((uint)l << 16);
}

// Pack A fragments (UNSHIFTED, exact K): frag f = (mtg*108 + s)*2 + pl,
// element at lane*8 + e.  A[m][k]: m = lane&31, k = (lane>>5)*8 + e,
// kk = 16*s + k  (flat K over [c][kh][kw]).
__global__ void packA_k(const float* __restrict__ Wp, ushort* __restrict__ Ap) {
    int id = blockIdx.x * 256 + threadIdx.x;
    if (id >= NMT * NST * 2 * 512) return;
    int e  = id & 7;
    int L  = (id >> 3) & 63;
    int f  = id >> 9;
    int pl = f & 1;
    int sf = f >> 1;
    int s   = sf % NST;
    int mtg = sf / NST;
    int kk = s * 16 + (L >> 5) * 8 + e;
    int p = mtg * 32 + (L & 31);
    float v = (p < NP) ? Wp[p * PS + kk] : 0.f;
    ushort h = f2bf(v);
    Ap[id] = pl ? f2bf(v - bf2f(h)) : h;
}

__global__ void colsum_k(const float* __restrict__ y,
                         float* __restrict__ cs, float* __restrict__ cs2) {
    int t = blockIdx.x * 256 + threadIdx.x;
    if (t >= HO * HW) return;
    int i = t / HW, w = t - i * HW;
    float s = 0.f, s2 = 0.f;
    for (int c = 0; c < CH; c++) {
        const float* base = y + c * HW * HW + i * HW + w;
        for (int dh = 0; dh < KS; dh++) {
            float v = base[dh * HW];
            s += v; s2 += v * v;
        }
    }
    cs[t] = s; cs2[t] = s2;
}

__global__ void window_k(const float* __restrict__ cs, const float* __restrict__ cs2,
                         float* __restrict__ sumY, float* __restrict__ denYa) {
    int t = blockIdx.x * 256 + threadIdx.x;
    if (t >= NPOS) return;
    int i = t / HO, j = t - i * HO;
    const float* r  = cs  + i * HW + j;
    const float* r2 = cs2 + i * HW + j;
    float s = 0.f, s2 = 0.f;
    for (int d = 0; d < KS; d++) { s += r[d]; s2 += r2[d]; }
    sumY[t] = s;
    float ips = 1.0f / (float)PS;
    denYa[t] = fabsf(s2 * ips - (s * ips) * (s * ips));
}

// ---------------- main exact-K MFMA correlation + argmax ----------------
// grid(4=jt, 153=row-triple, 7=mtg-pair). Block = 4 waves = 2 j-chunks (cw)
// x 2 mtg (mw). Wave: 32 patches x 64 positions (j = jb + 2n + t) x 3 rows.
// K = exact 1728 = 108 K16 steps; step s=3q+u, lane block b = 2s+kha ->
// row = b/3, sub = b%3 (per-lane constants via u-table).
// t absorbed into B via a one-ushort-shifted LDS copy (same offset, other
// array) -> A unshifted, all B-reads 4x aligned ds_read_b32, conflict-free.
__launch_bounds__(256, 3)
__global__ void corrx_k(const uint* __restrict__ yhl, const ushort* __restrict__ Ap,
                        const float* __restrict__ meanX, const float* __restrict__ denXa,
                        const float* __restrict__ sumY, const float* __restrict__ denYa,
                        ull* __restrict__ best) {
    // 4 planes: [0]=h copy0, [1]=h copy1(+1), [2]=l copy0, [3]=l copy1(+1)
    __shared__ ushort S[4 * 26 * 160];   // 33280 B

    const int tid  = threadIdx.x;
    const int lane = tid & 63;
    const int g    = tid >> 6;
    const int n    = lane & 31;     // MFMA column
    const int kha  = lane >> 5;     // k-half selector
    const int cw   = g & 1;
    const int mw   = g >> 1;
    static const int j0tab[4] = {0, 128, 256, 332};
    const int j0   = j0tab[blockIdx.x];
    const int i0   = blockIdx.y * 3;
    const int mtg  = blockIdx.z * 2 + mw;

    const int colbase = 64 * cw + 2 * n;
    // off[u] = rowadd*160 + 8*sub for this lane's kha
    const int off0 = kha ? 8         : 0;
    const int off1 = kha ? 160       : 16;
    const int off2 = kha ? 160 + 16  : 160 + 8;

    const ushort* ApW = Ap + (size_t)mtg * (NST * 2 * 512) + lane * 8;

    float16v acc0[3], acc1[3];
#pragma unroll
    for (int ri = 0; ri < 3; ri++) { acc0[ri] = (float16v)0.f; acc1[ri] = (float16v)0.f; }

    for (int c = 0; c < CH; c++) {
        __syncthreads();   // previous chunk fully consumed
        // stage 26 rows x 160 cols into 4 planes (h/l x shift0/shift1)
        for (int it = tid; it < 26 * 20; it += 256) {
            int row = it / 20;
            int g8  = (it - row * 20) * 8;
            int yr  = i0 + row;
            int gj  = j0 + g8;
            uint px[9];
            const uint* qp = yhl + c * HW * HW + yr * HW;
            if (yr < HW && gj + 8 < HW) {
                uint4 a = *(const uint4*)(qp + gj);
                uint4 b = *(const uint4*)(qp + gj + 4);
                px[0]=a.x; px[1]=a.y; px[2]=a.z; px[3]=a.w;
                px[4]=b.x; px[5]=b.y; px[6]=b.z; px[7]=b.w;
                px[8]=qp[gj + 8];
            } else {
#pragma unroll
                for (int k2 = 0; k2 < 9; k2++)
                    px[k2] = (yr < HW && gj + k2 < HW) ? qp[gj + k2] : 0u;
            }
            uint4 wh0, wh1, wl0, wl1;
            uint* wh0p = (uint*)&wh0; uint* wh1p = (uint*)&wh1;
            uint* wl0p = (uint*)&wl0; uint* wl1p = (uint*)&wl1;
#pragma unroll
            for (int k2 = 0; k2 < 4; k2++) {
                uint p0 = px[2*k2], p1 = px[2*k2+1], p2 = px[2*k2+2];
                wh0p[k2] = (p0 & 0xffffu) | (p1 << 16);
                wh1p[k2] = (p1 & 0xffffu) | (p2 << 16);
                wl0p[k2] = (p0 >> 16) | (p1 & 0xffff0000u);
                wl1p[k2] = (p1 >> 16) | (p2 & 0xffff0000u);
            }
            int base = row * 160 + g8;
            *(uint4*)&S[base]             = wh0;
            *(uint4*)&S[base + 4160]      = wh1;
            *(uint4*)&S[base + 8320]      = wl0;
            *(uint4*)&S[base + 12480]     = wl1;
        }
        __syncthreads();

        for (int q = 0; q < 12; q++) {
            const int rb = (2 * q) * 160 + colbase;
#pragma unroll
            for (int u = 0; u < 3; u++) {
                const ushort* fa = ApW + ((size_t)((c * 36 + 3 * q + u) * 2) << 9);
                short8 ah = *(const short8*)(fa);
                short8 al = *(const short8*)(fa + 512);
                const int offu = (u == 0) ? off0 : (u == 1) ? off1 : off2;
#pragma unroll
                for (int ri = 0; ri < 3; ri++) {
                    const int O = rb + ri * 160 + offu;   // even -> uint-aligned
                    union F { uint u4[4]; short8 v; } bh0, bh1, bl0, bl1;
                    const uint* p0 = (const uint*)(S + O);
                    const uint* p1 = (const uint*)(S + 4160 + O);
                    const uint* p2 = (const uint*)(S + 8320 + O);
                    const uint* p3 = (const uint*)(S + 12480 + O);
#pragma unroll
                    for (int w = 0; w < 4; w++) {
                        bh0.u4[w] = p0[w]; bh1.u4[w] = p1[w];
                        bl0.u4[w] = p2[w]; bl1.u4[w] = p3[w];
                    }
                    acc0[ri] = __builtin_amdgcn_mfma_f32_32x32x16_bf16(ah, bh0.v, acc0[ri], 0, 0, 0);
                    acc0[ri] = __builtin_amdgcn_mfma_f32_32x32x16_bf16(ah, bl0.v, acc0[ri], 0, 0, 0);
                    acc0[ri] = __builtin_amdgcn_mfma_f32_32x32x16_bf16(al, bh0.v, acc0[ri], 0, 0, 0);
                    acc1[ri] = __builtin_amdgcn_mfma_f32_32x32x16_bf16(ah, bh1.v, acc1[ri], 0, 0, 0);
                    acc1[ri] = __builtin_amdgcn_mfma_f32_32x32x16_bf16(ah, bl1.v, acc1[ri], 0, 0, 0);
                    acc1[ri] = __builtin_amdgcn_mfma_f32_32x32x16_bf16(al, bh1.v, acc1[ri], 0, 0, 0);
                }
            }
        }
    }

    // ---- epilogue: corr + packed argmax ----
    const float invps = 1.0f / (float)PS;
    const int pbase = mtg * 32;
    const int jb = j0 + 64 * cw;
    float mXv[16], dXv[16];
#pragma unroll
    for (int r = 0; r < 16; r++) {
        int p = pbase + (r & 3) + 8 * (r >> 2) + 4 * kha;
        bool ok = p < NP;
        mXv[r] = ok ? meanX[p] : 0.f;
        dXv[r] = ok ? denXa[p] : 0.f;
    }
    float sYv[3][2], dYv[3][2];
#pragma unroll
    for (int ri = 0; ri < 3; ri++) {
        bool iok = (i0 + ri) < HO;
        int ib = (i0 + ri) * HO;
#pragma unroll
        for (int t = 0; t < 2; t++) {
            int j = jb + 2 * n + t;
            bool ok = iok && (j < HO);
            sYv[ri][t] = ok ? sumY[ib + j] : 0.f;
            dYv[ri][t] = ok ? denYa[ib + j] : 0.f;
        }
    }
#pragma unroll
    for (int r = 0; r < 16; r++) {
        ull bp = 0ull;
#pragma unroll
        for (int ri = 0; ri < 3; ri++) {
            if ((i0 + ri) >= HO) continue;
#pragma unroll
            for (int t = 0; t < 2; t++) {
                int j = jb + 2 * n + t;
                if (j < HO) {
                    float xy = t ? acc1[ri][r] : acc0[ri][r];
                    float corr = (2.0f * (xy - mXv[r] * sYv[ri][t]) * invps + SIG)
                               / (dXv[r] + dYv[ri][t] + SIG);
                    uint ub = __float_as_uint(corr);
                    ub = (ub & 0x80000000u) ? ~ub : (ub | 0x80000000u);
                    uint idx = (uint)((i0 + ri) * HO + j);
                    ull pk = ((ull)ub << 32) | (uint)(~idx);
                    bp = pk > bp ? pk : bp;
                }
            }
        }
#pragma unroll
        for (int o = 1; o < 32; o <<= 1) {
            ull other = __shfl_xor(bp, o);
            bp = other > bp ? other : bp;
        }
        if (n == 0) {
            int p = pbase + (r & 3) + 8 * (r >> 2) + 4 * kha;
            if (p < NP) atomicMax(&best[p], bp);
        }
    }
}

// ---------------- gather ----------------
__global__ void gather_k(const float* __restrict__ y,
                         const ull* __restrict__ best,
                         float* __restrict__ out) {
    int p = blockIdx.x;
    uint idx = ~((uint)(best[p] & 0xFFFFFFFFull));
    int r = idx / HO, cc = idx - r * HO;
    int pr = p / 20, pc = p - pr * 20;
    for (int e = threadIdx.x; e < PS; e += 256) {
        int c = e / (KS * KS);
        int kh = (e / KS) % KS;
        int kw = e % KS;
        out[c * HW * HW + (pr * KS + kh) * HW + (pc * KS + kw)] =
            y[c * HW * HW + (r + kh) * HW + (cc + kw)];
    }
}

// ---------------- launch ----------------
extern "C" void kernel_launch(void* const* d_in, const int* in_sizes, int n_in,
                              void* d_out, int out_size, void* d_ws, size_t ws_size,
                              hipStream_t stream) {
    const float* x_dec = (const float*)d_in[0];
    const float* y_dec = (const float*)d_in[1];
    const float* y     = (const float*)d_in[2];
    float* out = (float*)d_out;

    char* ws = (char*)d_ws;
    size_t off = 0;
    auto carve = [&](size_t bytes) -> void* {
        void* p = ws + off;
        off += (bytes + 255) & ~(size_t)255;
        return p;
    };
    float* Wp    = (float*)carve((size_t)NP * PS * 4);              // 2.76 MB
    uint*  yhl   = (uint*)carve((size_t)CH * HW * HW * 4);          // 2.76 MB
    ushort* Ap   = (ushort*)carve((size_t)NMT * NST * 2 * 512 * 2); // 3.10 MB
    float* cs    = (float*)carve((size_t)HO * HW * 4);
    float* cs2   = (float*)carve((size_t)HO * HW * 4);
    float* sumY  = (float*)carve((size_t)NPOS * 4);
    float* denYa = (float*)carve((size_t)NPOS * 4);
    float* meanX = (float*)carve((size_t)NP * 4);
    float* denXa = (float*)carve((size_t)NP * 4);
    ull*   best  = (ull*)carve((size_t)NP * 8);

    hipMemsetAsync(best, 0, (size_t)NP * 8, stream);

    repack_k<<<(NP * PS + 255) / 256, 256, 0, stream>>>(x_dec, Wp);
    stats_k<<<NP, 256, 0, stream>>>(Wp, meanX, denXa);
    split_y_k<<<(CH * HW * HW + 255) / 256, 256, 0, stream>>>(y_dec, yhl);
    packA_k<<<(NMT * NST * 2 * 512 + 255) / 256, 256, 0, stream>>>(Wp, Ap);
    colsum_k<<<(HO * HW + 255) / 256, 256, 0, stream>>>(y_dec, cs, cs2);
    window_k<<<(NPOS + 255) / 256, 256, 0, stream>>>(cs, cs2, sumY, denYa);

    dim3 grid(4, 153, 7);
    corrx_k<<<grid, 256, 0, stream>>>(yhl, Ap, meanX, denXa, sumY, denYa, best);

    gather_k<<<NP, 256, 0, stream>>>(y, best, out);
}